// Round 1
// 908.919 us; speedup vs baseline: 1.0020x; 1.0020x over previous
//
#include <hip/hip_runtime.h>
#include <math.h>

// Problem constants (fixed by reference): B=2, S=2048, D=2048, H=16, kd=128
#define M_    4096   // B*S
#define D_    2048
#define NQKV  2304   // D + 2*kd
#define KD_   128
#define S_    2048

using bf16x8  = __attribute__((ext_vector_type(8))) __bf16;
using f32x4   = __attribute__((ext_vector_type(4))) float;
using ushort8 = __attribute__((ext_vector_type(8))) unsigned short;

// fp32 -> bf16 bits, round-to-nearest-even
__device__ __forceinline__ unsigned short f2bf(float f) {
  unsigned int u = __builtin_bit_cast(unsigned int, f);
  u += 0x7fffu + ((u >> 16) & 1u);
  return (unsigned short)(u >> 16);
}
__device__ __forceinline__ unsigned int pack2bf(float a, float b) {
  return (unsigned int)f2bf(a) | ((unsigned int)f2bf(b) << 16);
}

// async global->LDS, 16B per lane; LDS dst must be wave-uniform base + lane*16
#define GLL16(g, l) \
  __builtin_amdgcn_global_load_lds((__attribute__((address_space(1))) void*)(g), \
                                   (__attribute__((address_space(3))) void*)(l), 16, 0, 0)

// ---------------------------------------------------------------------------
// Prep 1: cast in_x fp32 -> bf16 (row-major [4096][2048])
__global__ void cast_x_kernel(const float* __restrict__ x, unsigned short* __restrict__ xb) {
  int i = (blockIdx.x * 256 + threadIdx.x) * 8;
  float4 a = *(const float4*)(x + i);
  float4 b = *(const float4*)(x + i + 4);
  ushort8 o;
  o[0]=f2bf(a.x); o[1]=f2bf(a.y); o[2]=f2bf(a.z); o[3]=f2bf(a.w);
  o[4]=f2bf(b.x); o[5]=f2bf(b.y); o[6]=f2bf(b.z); o[7]=f2bf(b.w);
  *(ushort8*)(xb + i) = o;
}

// ---------------------------------------------------------------------------
// Prep 2: fused weight transpose+cast:  Wt[n][k] = (n<2048 ? W_sc[k][n] : W_qkv[k][n-2048])
__global__ void prep_w_kernel(const float* __restrict__ Wsc, const float* __restrict__ Wqkv,
                              unsigned short* __restrict__ Wt) {
  __shared__ float t[32][33];
  int k0 = blockIdx.x * 32, n0 = blockIdx.y * 32;
  int tx = threadIdx.x, ty = threadIdx.y;
  #pragma unroll
  for (int i = 0; i < 32; i += 8) {
    int k = k0 + ty + i, n = n0 + tx;
    t[ty + i][tx] = (n < D_) ? Wsc[(size_t)k * D_ + n] : Wqkv[(size_t)k * NQKV + (n - D_)];
  }
  __syncthreads();
  #pragma unroll
  for (int i = 0; i < 32; i += 8) {
    int n = n0 + ty + i, k = k0 + tx;
    Wt[(size_t)n * D_ + k] = f2bf(t[tx][ty + i]);
  }
}

// ---------------------------------------------------------------------------
// Fused GEMM: C = Xb(4096x2048) * W(2048x4352) + bias
// m97 structure: 128x128 tile, BK=32, 4 waves; + T1 XCD-aware block swizzle
__global__ __launch_bounds__(256, 2) void gemm_fused_kernel(
    const unsigned short* __restrict__ X,   // [4096][2048] bf16
    const unsigned short* __restrict__ Wt,  // [4352][2048] bf16 (pre-transposed)
    const float* __restrict__ b_sc, const float* __restrict__ b_qkv,
    float* __restrict__ shortcut, unsigned short* __restrict__ qkv) {
  __shared__ alignas(16) unsigned short As[128 * 32];
  __shared__ alignas(16) unsigned short Bs[128 * 32];
  const int tid = threadIdx.x;
  const int lane = tid & 63, wid = tid >> 6;
  const int l16 = lane & 15, quad = lane >> 4;
  const int wm = (wid >> 1) * 64, wn = (wid & 1) * 64;
  // XCD swizzle: 1088 blocks, 8 XCDs, 136 contiguous wg each -> 4 m-panels/XCD in L2
  const int bid = blockIdx.x;
  const int wg = (bid & 7) * 136 + (bid >> 3);
  const int m0 = (wg / 34) * 128, n0 = (wg % 34) * 128;

  const int fa = tid * 16;
  const char* aSrc0 = (const char*)X  + (size_t)(m0 + (fa >> 6)) * 4096 + (fa & 63);
  const char* aSrc1 = aSrc0 + (size_t)64 * 4096;
  const char* bSrc0 = (const char*)Wt + (size_t)(n0 + (fa >> 6)) * 4096 + (fa & 63);
  const char* bSrc1 = bSrc0 + (size_t)64 * 4096;
  char* aDst0 = (char*)As + fa; char* aDst1 = aDst0 + 4096;
  char* bDst0 = (char*)Bs + fa; char* bDst1 = bDst0 + 4096;

  f32x4 acc[4][4] = {};
  for (int kt = 0; kt < 64; ++kt) {
    __syncthreads();
    GLL16(aSrc0, aDst0); GLL16(aSrc1, aDst1);
    GLL16(bSrc0, bDst0); GLL16(bSrc1, bDst1);
    aSrc0 += 64; aSrc1 += 64; bSrc0 += 64; bSrc1 += 64;
    __syncthreads();
    bf16x8 af[4], bfr[4];
    #pragma unroll
    for (int mi = 0; mi < 4; ++mi)
      af[mi] = *(const bf16x8*)(As + (wm + mi * 16 + l16) * 32 + quad * 8);
    #pragma unroll
    for (int ni = 0; ni < 4; ++ni)
      bfr[ni] = *(const bf16x8*)(Bs + (wn + ni * 16 + l16) * 32 + quad * 8);
    #pragma unroll
    for (int mi = 0; mi < 4; ++mi)
      #pragma unroll
      for (int ni = 0; ni < 4; ++ni)
        acc[mi][ni] = __builtin_amdgcn_mfma_f32_16x16x32_bf16(af[mi], bfr[ni], acc[mi][ni], 0, 0, 0);
  }

  #pragma unroll
  for (int ni = 0; ni < 4; ++ni) {
    int n = n0 + wn + ni * 16 + l16;
    float bias = (n < D_) ? b_sc[n] : b_qkv[n - D_];
    #pragma unroll
    for (int mi = 0; mi < 4; ++mi) {
      #pragma unroll
      for (int r = 0; r < 4; ++r) {
        int m = m0 + wm + mi * 16 + quad * 4 + r;
        float v = acc[mi][ni][r] + bias;
        if (n < D_) shortcut[(size_t)m * D_ + n] = v;
        else        qkv[(size_t)m * NQKV + (n - D_)] = f2bf(v);
      }
    }
  }
}

// ---------------------------------------------------------------------------
// Prep 3: Vt[b][d][t] = qkv[b*2048+t][2176+d]   (bf16 transpose, per batch)
__global__ void prep_vt_kernel(const unsigned short* __restrict__ qkv,
                               unsigned short* __restrict__ vt) {
  __shared__ unsigned short t[32][33];
  int b = blockIdx.z;
  int t0 = blockIdx.x * 32, d0 = blockIdx.y * 32;
  int tx = threadIdx.x, ty = threadIdx.y;
  #pragma unroll
  for (int i = 0; i < 32; i += 8)
    t[ty + i][tx] = qkv[(size_t)(b * S_ + t0 + ty + i) * NQKV + (D_ + KD_) + d0 + tx];
  __syncthreads();
  #pragma unroll
  for (int i = 0; i < 32; i += 8)
    vt[(size_t)(b * KD_ + d0 + ty + i) * S_ + t0 + tx] = t[tx][ty + i];
}

// ---------------------------------------------------------------------------
// Attention v2: TT=128 t-tile, Q in regs, SWAPPED QK^T (S^T fragments so each
// lane owns one q-row: float4 score stores, 2-shuffle softmax, b64 P pack).
// Ps is wave-private (each wave writes/reads only its own 16 q-rows) -> no
// barrier on the P path. 2 barriers/iter, 16 iters (was 3 x 32).
__global__ __launch_bounds__(256, 2) void attn_kernel(
    const unsigned short* __restrict__ qkv,  // [4096][2304] bf16
    const unsigned short* __restrict__ vt,   // [2][128][2048] bf16 (V^T)
    float* __restrict__ score, float* __restrict__ atten, float* __restrict__ res) {
  __shared__ alignas(16) unsigned short Ks[4 * 128 * 32];  // 32 KB [d-chunk][t][32 d]
  __shared__ alignas(16) unsigned short Vs[4 * 128 * 32];  // 32 KB [t-chunk][d][32 t]
  __shared__ alignas(16) unsigned short Ps[4 * 64 * 32];   // 16 KB [t-chunk][q][32 t]
  // 80 KB total -> 2 blocks/CU (160 KB LDS pool)

  const int tid = threadIdx.x;
  const int lane = tid & 63, wid = tid >> 6;
  const int l16 = lane & 15, quad = lane >> 4;
  // XCD swizzle: 1024 blocks -> 128 contiguous wg per XCD (4 bh-groups share K/V in L2)
  const int bid = blockIdx.x;
  const int wg = (bid & 7) * 128 + (bid >> 3);
  const int qt = wg & 31, bh = wg >> 5;
  const int b = bh >> 4, h = bh & 15;
  const int q0 = qt * 64;
  const int rr = tid >> 2, cc = (tid & 3) * 16;  // staging: row, byte-col within 64

  // Q tile -> registers (one-time; 16 rows x 128 d per wave)
  bf16x8 qf[4];
  {
    const unsigned short* qb = qkv + (size_t)(b * S_ + q0 + wid * 16 + l16) * NQKV + h * KD_ + quad * 8;
    #pragma unroll
    for (int kk = 0; kk < 4; ++kk) qf[kk] = *(const bf16x8*)(qb + kk * 32);
  }

  f32x4 acc_o[8] = {};
  float m_r = -1e30f, l_r = 0.f;
  const float inv_scale = 1.0f / 16384.0f;  // 1/(kd*kd)

  const char* kb0 = (const char*)qkv + (size_t)b * S_ * (NQKV * 2) + D_ * 2;
  const char* vb0 = (const char*)vt + (size_t)b * KD_ * S_ * 2;

  for (int tt = 0; tt < 16; ++tt) {
    const int t0 = tt * 128;
    __syncthreads();                        // all waves done reading prev K/V (and score stores drained under PV)
    #pragma unroll
    for (int i = 0; i < 8; ++i) {           // K tile: 128 t-rows x 128 d
      int kk = i >> 1, t = (i & 1) * 64 + rr;
      GLL16(kb0 + (size_t)(t0 + t) * (NQKV * 2) + kk * 64 + cc, (char*)Ks + i * 4096 + tid * 16);
    }
    #pragma unroll
    for (int i = 0; i < 8; ++i) {           // V^T tile: 128 d-rows x 128 t
      int kkt = i >> 1, d = (i & 1) * 64 + rr;
      GLL16(vb0 + (size_t)d * (S_ * 2) + t0 * 2 + kkt * 64 + cc, (char*)Vs + i * 4096 + tid * 16);
    }
    __syncthreads();                        // tiles ready

    // S^T = K Q^T scaled: sa[jt] holds rows t=jt*16+quad*4+r, col q=wid*16+l16
    f32x4 sa[8], sb[8];
    #pragma unroll
    for (int jt = 0; jt < 8; ++jt) {
      f32x4 a = {};
      #pragma unroll
      for (int kk = 0; kk < 4; ++kk) {
        bf16x8 kf = *(const bf16x8*)(Ks + kk * 4096 + (jt * 16 + l16) * 32 + quad * 8);
        a = __builtin_amdgcn_mfma_f32_16x16x32_bf16(kf, qf[kk], a, 0, 0, 0);
      }
      #pragma unroll
      for (int r = 0; r < 4; ++r) a[r] *= inv_scale;
      sa[jt] = a; sb[jt] = a;               // sb: pre-softmax copy for deferred store
    }

    // online softmax: all 32 in-lane values share q = wid*16+l16
    float mx = sa[0][0];
    #pragma unroll
    for (int jt = 0; jt < 8; ++jt)
      #pragma unroll
      for (int r = 0; r < 4; ++r) mx = fmaxf(mx, sa[jt][r]);
    mx = fmaxf(mx, __shfl_xor(mx, 16));
    mx = fmaxf(mx, __shfl_xor(mx, 32));
    float mn = fmaxf(m_r, mx);
    float alpha = __expf(m_r - mn);
    m_r = mn;
    float sm = 0.f;
    #pragma unroll
    for (int jt = 0; jt < 8; ++jt)
      #pragma unroll
      for (int r = 0; r < 4; ++r) { float p = __expf(sa[jt][r] - mn); sa[jt][r] = p; sm += p; }
    sm += __shfl_xor(sm, 16);
    sm += __shfl_xor(sm, 32);
    l_r = l_r * alpha + sm;
    // redistribute alpha from stat layout (q=l16) to O's C layout (q=quad*4+r)
    float al[4];
    #pragma unroll
    for (int r = 0; r < 4; ++r) al[r] = __shfl(alpha, quad * 4 + r);
    #pragma unroll
    for (int dn = 0; dn < 8; ++dn)
      #pragma unroll
      for (int r = 0; r < 4; ++r) acc_o[dn][r] *= al[r];

    // P -> LDS in A-operand layout; wave-private rows, no barrier needed
    {
      const int qrow = wid * 16 + l16;
      #pragma unroll
      for (int jt = 0; jt < 8; ++jt) {
        uint2 w; w.x = pack2bf(sa[jt][0], sa[jt][1]); w.y = pack2bf(sa[jt][2], sa[jt][3]);
        *(uint2*)(Ps + (jt >> 1) * 2048 + qrow * 32 + (jt & 1) * 16 + quad * 4) = w;
      }
    }

    // deferred score stores (pre-softmax), float4: q fixed per lane, t contiguous
    {
      float* sc = score + ((size_t)bh * S_ + q0 + wid * 16 + l16) * S_ + t0 + quad * 4;
      #pragma unroll
      for (int jt = 0; jt < 8; ++jt) *(f32x4*)(sc + jt * 16) = sb[jt];
    }

    // O += P V  (store-ack latency hides under these 36 ds_reads + 32 MFMAs)
    #pragma unroll
    for (int kkt = 0; kkt < 4; ++kkt) {
      bf16x8 pf = *(const bf16x8*)(Ps + kkt * 2048 + (wid * 16 + l16) * 32 + quad * 8);
      #pragma unroll
      for (int dn = 0; dn < 8; ++dn) {
        bf16x8 vf = *(const bf16x8*)(Vs + kkt * 4096 + (dn * 16 + l16) * 32 + quad * 8);
        acc_o[dn] = __builtin_amdgcn_mfma_f32_16x16x32_bf16(pf, vf, acc_o[dn], 0, 0, 0);
      }
    }
  }

  // epilogue: atten[b][h][q][d] and res[b][q][h*128+d]; l in stat layout -> shfl
  float lo[4];
  #pragma unroll
  for (int r = 0; r < 4; ++r) lo[r] = 1.0f / __shfl(l_r, quad * 4 + r);
  #pragma unroll
  for (int dn = 0; dn < 8; ++dn) {
    int d = dn * 16 + l16;
    #pragma unroll
    for (int r = 0; r < 4; ++r) {
      int q = q0 + wid * 16 + quad * 4 + r;
      float v = acc_o[dn][r] * lo[r];
      atten[((size_t)bh * S_ + q) * KD_ + d] = v;
      res[((size_t)b * S_ + q) * D_ + h * KD_ + d] = v;
    }
  }
}

// ---------------------------------------------------------------------------
extern "C" void kernel_launch(void* const* d_in, const int* in_sizes, int n_in,
                              void* d_out, int out_size, void* d_ws, size_t ws_size,
                              hipStream_t stream) {
  (void)in_sizes; (void)n_in; (void)out_size; (void)ws_size;
  const float* in_x  = (const float*)d_in[0];
  const float* W_sc  = (const float*)d_in[1];
  const float* b_sc  = (const float*)d_in[2];
  const float* W_qkv = (const float*)d_in[3];
  const float* b_qkv = (const float*)d_in[4];

  char* ws = (char*)d_ws;
  unsigned short* Xb  = (unsigned short*)ws;                          // 16,777,216 B
  unsigned short* Wt  = (unsigned short*)(ws + 16777216);             // 17,825,792 B
  unsigned short* qkv = (unsigned short*)(ws + 16777216 + 17825792);  // 18,874,368 B
  unsigned short* Vt  = (unsigned short*)(ws + 16777216 + 17825792 + 18874368);  // 1,048,576 B

  float* score    = (float*)d_out;            // 2*16*2048*2048
  float* atten    = score + 134217728;
  float* res      = atten + 8388608;
  float* shortcut = res + 8388608;

  cast_x_kernel<<<4096, 256, 0, stream>>>(in_x, Xb);
  prep_w_kernel<<<dim3(64, 136), dim3(32, 8), 0, stream>>>(W_sc, W_qkv, Wt);
  gemm_fused_kernel<<<1088, 256, 0, stream>>>(Xb, Wt, b_sc, b_qkv, shortcut, qkv);
  prep_vt_kernel<<<dim3(64, 4, 2), dim3(32, 8), 0, stream>>>(qkv, Vt);
  attn_kernel<<<1024, 256, 0, stream>>>(qkv, Vt, score, atten, res);
}

// Round 3
// 862.411 us; speedup vs baseline: 1.0561x; 1.0539x over previous
//
#include <hip/hip_runtime.h>
#include <math.h>

// Problem constants (fixed by reference): B=2, S=2048, D=2048, H=16, kd=128
#define M_    4096   // B*S
#define D_    2048
#define NQKV  2304   // D + 2*kd
#define KD_   128
#define S_    2048

using bf16x8  = __attribute__((ext_vector_type(8))) __bf16;
using f32x4   = __attribute__((ext_vector_type(4))) float;
using ushort8 = __attribute__((ext_vector_type(8))) unsigned short;

// fp32 -> bf16 bits, round-to-nearest-even
__device__ __forceinline__ unsigned short f2bf(float f) {
  unsigned int u = __builtin_bit_cast(unsigned int, f);
  u += 0x7fffu + ((u >> 16) & 1u);
  return (unsigned short)(u >> 16);
}
__device__ __forceinline__ unsigned int pack2bf(float a, float b) {
  return (unsigned int)f2bf(a) | ((unsigned int)f2bf(b) << 16);
}

// async global->LDS, 16B per lane; LDS dst must be wave-uniform base + lane*16
#define GLL16(g, l) \
  __builtin_amdgcn_global_load_lds((__attribute__((address_space(1))) void*)(g), \
                                   (__attribute__((address_space(3))) void*)(l), 16, 0, 0)

// compiler-only memory fence: forbids LDS access reordering across the overlay's
// type-punned views (f32x4 scratch vs uint2/bf16x8 P tiles) without runtime cost
#define CFENCE() asm volatile("" ::: "memory")

// ---------------------------------------------------------------------------
// Prep 1: cast in_x fp32 -> bf16 (row-major [4096][2048])
__global__ void cast_x_kernel(const float* __restrict__ x, unsigned short* __restrict__ xb) {
  int i = (blockIdx.x * 256 + threadIdx.x) * 8;
  float4 a = *(const float4*)(x + i);
  float4 b = *(const float4*)(x + i + 4);
  ushort8 o;
  o[0]=f2bf(a.x); o[1]=f2bf(a.y); o[2]=f2bf(a.z); o[3]=f2bf(a.w);
  o[4]=f2bf(b.x); o[5]=f2bf(b.y); o[6]=f2bf(b.z); o[7]=f2bf(b.w);
  *(ushort8*)(xb + i) = o;
}

// ---------------------------------------------------------------------------
// Prep 2: fused weight transpose+cast:  Wt[n][k] = (n<2048 ? W_sc[k][n] : W_qkv[k][n-2048])
__global__ void prep_w_kernel(const float* __restrict__ Wsc, const float* __restrict__ Wqkv,
                              unsigned short* __restrict__ Wt) {
  __shared__ float t[32][33];
  int k0 = blockIdx.x * 32, n0 = blockIdx.y * 32;
  int tx = threadIdx.x, ty = threadIdx.y;
  #pragma unroll
  for (int i = 0; i < 32; i += 8) {
    int k = k0 + ty + i, n = n0 + tx;
    t[ty + i][tx] = (n < D_) ? Wsc[(size_t)k * D_ + n] : Wqkv[(size_t)k * NQKV + (n - D_)];
  }
  __syncthreads();
  #pragma unroll
  for (int i = 0; i < 32; i += 8) {
    int n = n0 + ty + i, k = k0 + tx;
    Wt[(size_t)n * D_ + k] = f2bf(t[tx][ty + i]);
  }
}

// ---------------------------------------------------------------------------
// Fused GEMM: C = Xb(4096x2048) * W(2048x4352) + bias  (unchanged)
__global__ __launch_bounds__(256, 2) void gemm_fused_kernel(
    const unsigned short* __restrict__ X,   // [4096][2048] bf16
    const unsigned short* __restrict__ Wt,  // [4352][2048] bf16 (pre-transposed)
    const float* __restrict__ b_sc, const float* __restrict__ b_qkv,
    float* __restrict__ shortcut, unsigned short* __restrict__ qkv) {
  __shared__ alignas(16) unsigned short As[128 * 32];
  __shared__ alignas(16) unsigned short Bs[128 * 32];
  const int tid = threadIdx.x;
  const int lane = tid & 63, wid = tid >> 6;
  const int l16 = lane & 15, quad = lane >> 4;
  const int wm = (wid >> 1) * 64, wn = (wid & 1) * 64;
  const int bid = blockIdx.x;
  const int wg = (bid & 7) * 136 + (bid >> 3);
  const int m0 = (wg / 34) * 128, n0 = (wg % 34) * 128;

  const int fa = tid * 16;
  const char* aSrc0 = (const char*)X  + (size_t)(m0 + (fa >> 6)) * 4096 + (fa & 63);
  const char* aSrc1 = aSrc0 + (size_t)64 * 4096;
  const char* bSrc0 = (const char*)Wt + (size_t)(n0 + (fa >> 6)) * 4096 + (fa & 63);
  const char* bSrc1 = bSrc0 + (size_t)64 * 4096;
  char* aDst0 = (char*)As + fa; char* aDst1 = aDst0 + 4096;
  char* bDst0 = (char*)Bs + fa; char* bDst1 = bDst0 + 4096;

  f32x4 acc[4][4] = {};
  for (int kt = 0; kt < 64; ++kt) {
    __syncthreads();
    GLL16(aSrc0, aDst0); GLL16(aSrc1, aDst1);
    GLL16(bSrc0, bDst0); GLL16(bSrc1, bDst1);
    aSrc0 += 64; aSrc1 += 64; bSrc0 += 64; bSrc1 += 64;
    __syncthreads();
    bf16x8 af[4], bfr[4];
    #pragma unroll
    for (int mi = 0; mi < 4; ++mi)
      af[mi] = *(const bf16x8*)(As + (wm + mi * 16 + l16) * 32 + quad * 8);
    #pragma unroll
    for (int ni = 0; ni < 4; ++ni)
      bfr[ni] = *(const bf16x8*)(Bs + (wn + ni * 16 + l16) * 32 + quad * 8);
    #pragma unroll
    for (int mi = 0; mi < 4; ++mi)
      #pragma unroll
      for (int ni = 0; ni < 4; ++ni)
        acc[mi][ni] = __builtin_amdgcn_mfma_f32_16x16x32_bf16(af[mi], bfr[ni], acc[mi][ni], 0, 0, 0);
  }

  #pragma unroll
  for (int ni = 0; ni < 4; ++ni) {
    int n = n0 + wn + ni * 16 + l16;
    float bias = (n < D_) ? b_sc[n] : b_qkv[n - D_];
    #pragma unroll
    for (int mi = 0; mi < 4; ++mi) {
      #pragma unroll
      for (int r = 0; r < 4; ++r) {
        int m = m0 + wm + mi * 16 + quad * 4 + r;
        float v = acc[mi][ni][r] + bias;
        if (n < D_) shortcut[(size_t)m * D_ + n] = v;
        else        qkv[(size_t)m * NQKV + (n - D_)] = f2bf(v);
      }
    }
  }
}

// ---------------------------------------------------------------------------
// Prep 3: Vt[b][d][t] = qkv[b*2048+t][2176+d]   (bf16 transpose, per batch)
__global__ void prep_vt_kernel(const unsigned short* __restrict__ qkv,
                               unsigned short* __restrict__ vt) {
  __shared__ unsigned short t[32][33];
  int b = blockIdx.z;
  int t0 = blockIdx.x * 32, d0 = blockIdx.y * 32;
  int tx = threadIdx.x, ty = threadIdx.y;
  #pragma unroll
  for (int i = 0; i < 32; i += 8)
    t[ty + i][tx] = qkv[(size_t)(b * S_ + t0 + ty + i) * NQKV + (D_ + KD_) + d0 + tx];
  __syncthreads();
  #pragma unroll
  for (int i = 0; i < 32; i += 8)
    vt[(size_t)(b * KD_ + d0 + ty + i) * S_ + t0 + tx] = t[tx][ty + i];
}

// ---------------------------------------------------------------------------
// Attention v3b: v2 structure; score-store path rebuilt for full-line writes.
// v2 stored 64B per 128B line per instruction -> TCC read-for-ownership on
// every score line (+537MB hidden fetch) + L2 thrash of the MQA K/V set.
// Here: pre-softmax fragments round-trip through a wave-private LDS scratch
// (overlaid on Ps, dead at that point; XOR-swizzled, b128 both phases) so each
// store instruction covers 8 rows x 128B full lines, nontemporal.
// v3b hardening: CFENCE() between the type-punned overlay phases (TBAA).
__global__ __launch_bounds__(256, 2) void attn_kernel(
    const unsigned short* __restrict__ qkv,  // [4096][2304] bf16
    const unsigned short* __restrict__ vt,   // [2][128][2048] bf16 (V^T)
    float* __restrict__ score, float* __restrict__ atten, float* __restrict__ res) {
  __shared__ alignas(16) unsigned short Ks[4 * 128 * 32];  // 32 KB [d-chunk][t][32 d]
  __shared__ alignas(16) unsigned short Vs[4 * 128 * 32];  // 32 KB [t-chunk][d][32 t]
  __shared__ alignas(16) unsigned short Ps[4 * 64 * 32];   // 16 KB [t-chunk][q][32 t]
  // 80 KB total -> 2 blocks/CU

  const int tid = threadIdx.x;
  const int lane = tid & 63, wid = tid >> 6;
  const int l16 = lane & 15, quad = lane >> 4;
  const int bid = blockIdx.x;
  const int wg = (bid & 7) * 128 + (bid >> 3);
  const int qt = wg & 31, bh = wg >> 5;
  const int b = bh >> 4, h = bh & 15;
  const int q0 = qt * 64;
  const int rr = tid >> 2, cc = (tid & 3) * 16;  // staging: row, byte-col within 64

  // Q tile -> registers (one-time; 16 rows x 128 d per wave)
  bf16x8 qf[4];
  {
    const unsigned short* qb = qkv + (size_t)(b * S_ + q0 + wid * 16 + l16) * NQKV + h * KD_ + quad * 8;
    #pragma unroll
    for (int kk = 0; kk < 4; ++kk) qf[kk] = *(const bf16x8*)(qb + kk * 32);
  }

  f32x4 acc_o[8] = {};
  float m_r = -1e30f, l_r = 0.f;
  const float inv_scale = 1.0f / 16384.0f;  // 1/(kd*kd)

  const char* kb0 = (const char*)qkv + (size_t)b * S_ * (NQKV * 2) + D_ * 2;
  const char* vb0 = (const char*)vt + (size_t)b * KD_ * S_ * 2;
  // wave-private f32 scratch overlaid on Ps (this wave's own bytes only)
  float* scr = (float*)Ps;

  for (int tt = 0; tt < 16; ++tt) {
    const int t0 = tt * 128;
    __syncthreads();                        // all waves done reading prev K/V
    #pragma unroll
    for (int i = 0; i < 8; ++i) {           // K tile: 128 t-rows x 128 d
      int kk = i >> 1, t = (i & 1) * 64 + rr;
      GLL16(kb0 + (size_t)(t0 + t) * (NQKV * 2) + kk * 64 + cc, (char*)Ks + i * 4096 + tid * 16);
    }
    #pragma unroll
    for (int i = 0; i < 8; ++i) {           // V^T tile: 128 d-rows x 128 t
      int kkt = i >> 1, d = (i & 1) * 64 + rr;
      GLL16(vb0 + (size_t)d * (S_ * 2) + t0 * 2 + kkt * 64 + cc, (char*)Vs + i * 4096 + tid * 16);
    }
    __syncthreads();                        // tiles ready

    // S^T = K Q^T scaled: sa[jt] holds rows t=jt*16+quad*4+r, col q=wid*16+l16
    f32x4 sa[8];
    #pragma unroll
    for (int jt = 0; jt < 8; ++jt) {
      f32x4 a = {};
      #pragma unroll
      for (int kk = 0; kk < 4; ++kk) {
        bf16x8 kf = *(const bf16x8*)(Ks + kk * 4096 + (jt * 16 + l16) * 32 + quad * 8);
        a = __builtin_amdgcn_mfma_f32_16x16x32_bf16(kf, qf[kk], a, 0, 0, 0);
      }
      #pragma unroll
      for (int r = 0; r < 4; ++r) a[r] *= inv_scale;
      sa[jt] = a;
    }

    // row max first (reads sa pre-exp; all 32 in-lane values share q=wid*16+l16)
    float mx = sa[0][0];
    #pragma unroll
    for (int jt = 0; jt < 8; ++jt)
      #pragma unroll
      for (int r = 0; r < 4; ++r) mx = fmaxf(mx, sa[jt][r]);
    mx = fmaxf(mx, __shfl_xor(mx, 16));
    mx = fmaxf(mx, __shfl_xor(mx, 32));
    float mn = fmaxf(m_r, mx);
    float alpha = __expf(m_r - mn);
    m_r = mn;

    // ---- score store, full-128B-line form, via wave-private LDS scratch ----
    // scratch layout: addrF(row,t') = (row>>2)*1024 + wid*256 + (row&3)*64
    //                                 + (t' ^ ((row&7)<<2)), row in 0..15, t' in 0..63
    #pragma unroll
    for (int hh = 0; hh < 2; ++hh) {
      #pragma unroll
      for (int j = 0; j < 4; ++j) {          // write 4 fragments (row = l16)
        int tp = j * 16 + quad * 4;
        int idx = ((l16 >> 2) * 1024) + wid * 256 + (l16 & 3) * 64 + (tp ^ ((l16 & 7) << 2));
        *(f32x4*)(scr + idx) = sa[hh * 4 + j];
      }
      CFENCE();
      #pragma unroll
      for (int i = 0; i < 4; ++i) {          // read back row-major, store full lines
        int row = (i & 1) * 8 + (lane >> 3);
        int tp = (i >> 1) * 32 + (lane & 7) * 4;
        int idx = ((row >> 2) * 1024) + wid * 256 + (row & 3) * 64 + (tp ^ ((row & 7) << 2));
        f32x4 vv = *(const f32x4*)(scr + idx);
        float* dst = score + ((size_t)bh * S_ + q0 + wid * 16 + row) * S_ + t0 + hh * 64 + tp;
        __builtin_nontemporal_store(vv, (f32x4*)dst);   // 8 lanes x 16B = 128B/row, 8 rows
      }
      CFENCE();
    }

    // exponentiate + row sum (overwrites sa; scratch already read out)
    float sm = 0.f;
    #pragma unroll
    for (int jt = 0; jt < 8; ++jt)
      #pragma unroll
      for (int r = 0; r < 4; ++r) { float p = __expf(sa[jt][r] - mn); sa[jt][r] = p; sm += p; }
    sm += __shfl_xor(sm, 16);
    sm += __shfl_xor(sm, 32);
    l_r = l_r * alpha + sm;
    // redistribute alpha from stat layout (q=l16) to O's C layout (q=quad*4+r)
    float al[4];
    #pragma unroll
    for (int r = 0; r < 4; ++r) al[r] = __shfl(alpha, quad * 4 + r);
    #pragma unroll
    for (int dn = 0; dn < 8; ++dn)
      #pragma unroll
      for (int r = 0; r < 4; ++r) acc_o[dn][r] *= al[r];

    // P -> LDS in A-operand layout; wave-private rows (same bytes as scratch,
    // sequential within wave; CFENCE above pins the order), no barrier needed
    {
      const int qrow = wid * 16 + l16;
      #pragma unroll
      for (int jt = 0; jt < 8; ++jt) {
        uint2 w; w.x = pack2bf(sa[jt][0], sa[jt][1]); w.y = pack2bf(sa[jt][2], sa[jt][3]);
        *(uint2*)(Ps + (jt >> 1) * 2048 + qrow * 32 + (jt & 1) * 16 + quad * 4) = w;
      }
    }
    CFENCE();

    // O += P V  (score-store ack latency hides under these ds_reads + MFMAs)
    #pragma unroll
    for (int kkt = 0; kkt < 4; ++kkt) {
      bf16x8 pf = *(const bf16x8*)(Ps + kkt * 2048 + (wid * 16 + l16) * 32 + quad * 8);
      #pragma unroll
      for (int dn = 0; dn < 8; ++dn) {
        bf16x8 vf = *(const bf16x8*)(Vs + kkt * 4096 + (dn * 16 + l16) * 32 + quad * 8);
        acc_o[dn] = __builtin_amdgcn_mfma_f32_16x16x32_bf16(pf, vf, acc_o[dn], 0, 0, 0);
      }
    }
  }

  // epilogue: atten[b][h][q][d] and res[b][q][h*128+d]; l in stat layout -> shfl
  float lo[4];
  #pragma unroll
  for (int r = 0; r < 4; ++r) lo[r] = 1.0f / __shfl(l_r, quad * 4 + r);
  #pragma unroll
  for (int dn = 0; dn < 8; ++dn) {
    int d = dn * 16 + l16;
    #pragma unroll
    for (int r = 0; r < 4; ++r) {
      int q = q0 + wid * 16 + quad * 4 + r;
      float v = acc_o[dn][r] * lo[r];
      atten[((size_t)bh * S_ + q) * KD_ + d] = v;
      res[((size_t)b * S_ + q) * D_ + h * KD_ + d] = v;
    }
  }
}

// ---------------------------------------------------------------------------
extern "C" void kernel_launch(void* const* d_in, const int* in_sizes, int n_in,
                              void* d_out, int out_size, void* d_ws, size_t ws_size,
                              hipStream_t stream) {
  (void)in_sizes; (void)n_in; (void)out_size; (void)ws_size;
  const float* in_x  = (const float*)d_in[0];
  const float* W_sc  = (const float*)d_in[1];
  const float* b_sc  = (const float*)d_in[2];
  const float* W_qkv = (const float*)d_in[3];
  const float* b_qkv = (const float*)d_in[4];

  char* ws = (char*)d_ws;
  unsigned short* Xb  = (unsigned short*)ws;                          // 16,777,216 B
  unsigned short* Wt  = (unsigned short*)(ws + 16777216);             // 17,825,792 B
  unsigned short* qkv = (unsigned short*)(ws + 16777216 + 17825792);  // 18,874,368 B
  unsigned short* Vt  = (unsigned short*)(ws + 16777216 + 17825792 + 18874368);  // 1,048,576 B

  float* score    = (float*)d_out;            // 2*16*2048*2048
  float* atten    = score + 134217728;
  float* res      = atten + 8388608;
  float* shortcut = res + 8388608;

  cast_x_kernel<<<4096, 256, 0, stream>>>(in_x, Xb);
  prep_w_kernel<<<dim3(64, 136), dim3(32, 8), 0, stream>>>(W_sc, W_qkv, Wt);
  gemm_fused_kernel<<<1088, 256, 0, stream>>>(Xb, Wt, b_sc, b_qkv, shortcut, qkv);
  prep_vt_kernel<<<dim3(64, 4, 2), dim3(32, 8), 0, stream>>>(qkv, Vt);
  attn_kernel<<<1024, 256, 0, stream>>>(qkv, Vt, score, atten, res);
}

// Round 4
// 861.866 us; speedup vs baseline: 1.0568x; 1.0006x over previous
//
#include <hip/hip_runtime.h>
#include <math.h>

// Problem constants (fixed by reference): B=2, S=2048, D=2048, H=16, kd=128
#define M_    4096   // B*S
#define D_    2048
#define NQKV  2304   // D + 2*kd
#define KD_   128
#define S_    2048

using bf16x8  = __attribute__((ext_vector_type(8))) __bf16;
using f32x4   = __attribute__((ext_vector_type(4))) float;
using ushort8 = __attribute__((ext_vector_type(8))) unsigned short;

// fp32 -> bf16 bits, round-to-nearest-even
__device__ __forceinline__ unsigned short f2bf(float f) {
  unsigned int u = __builtin_bit_cast(unsigned int, f);
  u += 0x7fffu + ((u >> 16) & 1u);
  return (unsigned short)(u >> 16);
}
__device__ __forceinline__ unsigned int pack2bf(float a, float b) {
  return (unsigned int)f2bf(a) | ((unsigned int)f2bf(b) << 16);
}

// async global->LDS, 16B per lane; LDS dst must be wave-uniform base + lane*16
#define GLL16(g, l) \
  __builtin_amdgcn_global_load_lds((__attribute__((address_space(1))) void*)(g), \
                                   (__attribute__((address_space(3))) void*)(l), 16, 0, 0)

// compiler-only memory fence (TBAA guard across type-punned LDS overlay views)
#define CFENCE() asm volatile("" ::: "memory")

// ---------------------------------------------------------------------------
// Prep 1: cast in_x fp32 -> bf16 (row-major [4096][2048])
__global__ void cast_x_kernel(const float* __restrict__ x, unsigned short* __restrict__ xb) {
  int i = (blockIdx.x * 256 + threadIdx.x) * 8;
  float4 a = *(const float4*)(x + i);
  float4 b = *(const float4*)(x + i + 4);
  ushort8 o;
  o[0]=f2bf(a.x); o[1]=f2bf(a.y); o[2]=f2bf(a.z); o[3]=f2bf(a.w);
  o[4]=f2bf(b.x); o[5]=f2bf(b.y); o[6]=f2bf(b.z); o[7]=f2bf(b.w);
  *(ushort8*)(xb + i) = o;
}

// ---------------------------------------------------------------------------
// Prep 2: fused weight transpose+cast:  Wt[n][k] = (n<2048 ? W_sc[k][n] : W_qkv[k][n-2048])
__global__ void prep_w_kernel(const float* __restrict__ Wsc, const float* __restrict__ Wqkv,
                              unsigned short* __restrict__ Wt) {
  __shared__ float t[32][33];
  int k0 = blockIdx.x * 32, n0 = blockIdx.y * 32;
  int tx = threadIdx.x, ty = threadIdx.y;
  #pragma unroll
  for (int i = 0; i < 32; i += 8) {
    int k = k0 + ty + i, n = n0 + tx;
    t[ty + i][tx] = (n < D_) ? Wsc[(size_t)k * D_ + n] : Wqkv[(size_t)k * NQKV + (n - D_)];
  }
  __syncthreads();
  #pragma unroll
  for (int i = 0; i < 32; i += 8) {
    int n = n0 + ty + i, k = k0 + tx;
    Wt[(size_t)n * D_ + k] = f2bf(t[tx][ty + i]);
  }
}

// ---------------------------------------------------------------------------
// Fused GEMM: C = Xb(4096x2048) * W(2048x4352) + bias  (unchanged)
__global__ __launch_bounds__(256, 2) void gemm_fused_kernel(
    const unsigned short* __restrict__ X,   // [4096][2048] bf16
    const unsigned short* __restrict__ Wt,  // [4352][2048] bf16 (pre-transposed)
    const float* __restrict__ b_sc, const float* __restrict__ b_qkv,
    float* __restrict__ shortcut, unsigned short* __restrict__ qkv) {
  __shared__ alignas(16) unsigned short As[128 * 32];
  __shared__ alignas(16) unsigned short Bs[128 * 32];
  const int tid = threadIdx.x;
  const int lane = tid & 63, wid = tid >> 6;
  const int l16 = lane & 15, quad = lane >> 4;
  const int wm = (wid >> 1) * 64, wn = (wid & 1) * 64;
  const int bid = blockIdx.x;
  const int wg = (bid & 7) * 136 + (bid >> 3);
  const int m0 = (wg / 34) * 128, n0 = (wg % 34) * 128;

  const int fa = tid * 16;
  const char* aSrc0 = (const char*)X  + (size_t)(m0 + (fa >> 6)) * 4096 + (fa & 63);
  const char* aSrc1 = aSrc0 + (size_t)64 * 4096;
  const char* bSrc0 = (const char*)Wt + (size_t)(n0 + (fa >> 6)) * 4096 + (fa & 63);
  const char* bSrc1 = bSrc0 + (size_t)64 * 4096;
  char* aDst0 = (char*)As + fa; char* aDst1 = aDst0 + 4096;
  char* bDst0 = (char*)Bs + fa; char* bDst1 = bDst0 + 4096;

  f32x4 acc[4][4] = {};
  for (int kt = 0; kt < 64; ++kt) {
    __syncthreads();
    GLL16(aSrc0, aDst0); GLL16(aSrc1, aDst1);
    GLL16(bSrc0, bDst0); GLL16(bSrc1, bDst1);
    aSrc0 += 64; aSrc1 += 64; bSrc0 += 64; bSrc1 += 64;
    __syncthreads();
    bf16x8 af[4], bfr[4];
    #pragma unroll
    for (int mi = 0; mi < 4; ++mi)
      af[mi] = *(const bf16x8*)(As + (wm + mi * 16 + l16) * 32 + quad * 8);
    #pragma unroll
    for (int ni = 0; ni < 4; ++ni)
      bfr[ni] = *(const bf16x8*)(Bs + (wn + ni * 16 + l16) * 32 + quad * 8);
    #pragma unroll
    for (int mi = 0; mi < 4; ++mi)
      #pragma unroll
      for (int ni = 0; ni < 4; ++ni)
        acc[mi][ni] = __builtin_amdgcn_mfma_f32_16x16x32_bf16(af[mi], bfr[ni], acc[mi][ni], 0, 0, 0);
  }

  #pragma unroll
  for (int ni = 0; ni < 4; ++ni) {
    int n = n0 + wn + ni * 16 + l16;
    float bias = (n < D_) ? b_sc[n] : b_qkv[n - D_];
    #pragma unroll
    for (int mi = 0; mi < 4; ++mi) {
      #pragma unroll
      for (int r = 0; r < 4; ++r) {
        int m = m0 + wm + mi * 16 + quad * 4 + r;
        float v = acc[mi][ni][r] + bias;
        if (n < D_) shortcut[(size_t)m * D_ + n] = v;
        else        qkv[(size_t)m * NQKV + (n - D_)] = f2bf(v);
      }
    }
  }
}

// ---------------------------------------------------------------------------
// Prep 3: Vt[b][d][t] = qkv[b*2048+t][2176+d]   (bf16 transpose, per batch)
__global__ void prep_vt_kernel(const unsigned short* __restrict__ qkv,
                               unsigned short* __restrict__ vt) {
  __shared__ unsigned short t[32][33];
  int b = blockIdx.z;
  int t0 = blockIdx.x * 32, d0 = blockIdx.y * 32;
  int tx = threadIdx.x, ty = threadIdx.y;
  #pragma unroll
  for (int i = 0; i < 32; i += 8)
    t[ty + i][tx] = qkv[(size_t)(b * S_ + t0 + ty + i) * NQKV + (D_ + KD_) + d0 + tx];
  __syncthreads();
  #pragma unroll
  for (int i = 0; i < 32; i += 8)
    vt[(size_t)(b * KD_ + d0 + ty + i) * S_ + t0 + tx] = t[tx][ty + i];
}

// ---------------------------------------------------------------------------
// Attention v4: v3b numerics/output path, restructured as T3-lite 2-phase
// double-buffered prefetch. TT=64 per tile, 32 iterations. Per iter: ISSUE
// next tile's global_load_lds into buf^1 first, run the full compute phase on
// buf, then ONE __syncthreads(). The prefetch has the whole compute phase
// (~2000 cy) to land, so the barrier's vmcnt(0) drain is nearly free —
// removes v3b's per-iteration exposed staging latency (issue->drain with
// zero compute between). LDS: Ks 2x16KB + Vs 2x16KB + Ps 8KB = 72KB -> 2 blk/CU.
__global__ __launch_bounds__(256, 2) void attn_kernel(
    const unsigned short* __restrict__ qkv,  // [4096][2304] bf16
    const unsigned short* __restrict__ vt,   // [2][128][2048] bf16 (V^T)
    float* __restrict__ score, float* __restrict__ atten, float* __restrict__ res) {
  __shared__ alignas(16) unsigned short Ks[2][4 * 64 * 32];   // [buf][kk][t][32 d]
  __shared__ alignas(16) unsigned short Vs[2][2 * 128 * 32];  // [buf][kkt][d][32 t]
  __shared__ alignas(16) unsigned short Ps[2 * 64 * 32];      // [kkt][q][32 t]  8 KB

  const int tid = threadIdx.x;
  const int lane = tid & 63, wid = tid >> 6;
  const int l16 = lane & 15, quad = lane >> 4;
  const int bid = blockIdx.x;
  const int wg = (bid & 7) * 128 + (bid >> 3);
  const int qt = wg & 31, bh = wg >> 5;
  const int b = bh >> 4, h = bh & 15;
  const int q0 = qt * 64;
  const int rr = tid >> 2, cc = (tid & 3) * 16;  // staging: row, byte-col within 64B

  // Q tile -> registers (one-time; 16 rows x 128 d per wave)
  bf16x8 qf[4];
  {
    const unsigned short* qb = qkv + (size_t)(b * S_ + q0 + wid * 16 + l16) * NQKV + h * KD_ + quad * 8;
    #pragma unroll
    for (int kk = 0; kk < 4; ++kk) qf[kk] = *(const bf16x8*)(qb + kk * 32);
  }

  f32x4 acc_o[8] = {};
  float m_r = -1e30f, l_r = 0.f;
  const float inv_scale = 1.0f / 16384.0f;  // 1/(kd*kd)

  const char* kb0 = (const char*)qkv + (size_t)b * S_ * (NQKV * 2) + D_ * 2;
  const char* vb0 = (const char*)vt + (size_t)b * KD_ * S_ * 2;
  // wave-private f32 scratch overlaid on Ps (exactly this wave's own bytes:
  // floats (g>>8)*1024 + wid*256 + (g&255), g in [0,512))
  float* scr = (float*)Ps;

  // STAGE(buf, t0): K tile 64t x 128d, V^T tile 128d x 64t, 4+4 GLL16/thread
  #define STAGE_KV(bufi, tbase) do {                                           \
    char* kd_ = (char*)Ks + (bufi) * 16384 + tid * 16;                         \
    char* vd_ = (char*)Vs + (bufi) * 16384 + tid * 16;                         \
    _Pragma("unroll")                                                          \
    for (int i_ = 0; i_ < 4; ++i_)                                             \
      GLL16(kb0 + (size_t)((tbase) + rr) * (NQKV * 2) + i_ * 64 + cc,          \
            kd_ + i_ * 4096);                                                  \
    _Pragma("unroll")                                                          \
    for (int i_ = 0; i_ < 4; ++i_)                                             \
      GLL16(vb0 + (size_t)((i_ & 1) * 64 + rr) * (S_ * 2) + (tbase) * 2        \
                + (i_ >> 1) * 64 + cc,                                         \
            vd_ + i_ * 4096);                                                  \
  } while (0)

  STAGE_KV(0, 0);          // prologue: tile 0 into buf 0
  __syncthreads();         // vmcnt(0) drained: tile 0 ready

  for (int tt = 0; tt < 32; ++tt) {
    const int buf = tt & 1;
    const int t0 = tt * 64;
    if (tt + 1 < 32) STAGE_KV(buf ^ 1, t0 + 64);   // prefetch next tile NOW

    // S^T = K Q^T scaled: sa[jt] holds rows t=jt*16+quad*4+r, col q=wid*16+l16
    const unsigned short* ksb = &Ks[buf][0];
    const unsigned short* vsb = &Vs[buf][0];
    f32x4 sa[4];
    #pragma unroll
    for (int jt = 0; jt < 4; ++jt) {
      f32x4 a = {};
      #pragma unroll
      for (int kk = 0; kk < 4; ++kk) {
        bf16x8 kf = *(const bf16x8*)(ksb + kk * 2048 + (jt * 16 + l16) * 32 + quad * 8);
        a = __builtin_amdgcn_mfma_f32_16x16x32_bf16(kf, qf[kk], a, 0, 0, 0);
      }
      #pragma unroll
      for (int r = 0; r < 4; ++r) a[r] *= inv_scale;
      sa[jt] = a;
    }

    // row max (all 16 in-lane values share q=wid*16+l16), then 2 shuffles
    float mx = sa[0][0];
    #pragma unroll
    for (int jt = 0; jt < 4; ++jt)
      #pragma unroll
      for (int r = 0; r < 4; ++r) mx = fmaxf(mx, sa[jt][r]);
    mx = fmaxf(mx, __shfl_xor(mx, 16));
    mx = fmaxf(mx, __shfl_xor(mx, 32));
    float mn = fmaxf(m_r, mx);
    float alpha = __expf(m_r - mn);
    m_r = mn;

    // ---- score store, full-128B-line form, via wave-private LDS scratch ----
    // per hh: 16 rows x 32 t' (2KB wave share); g(row,t') = row*32 + (t'^((row&7)<<2))
    #pragma unroll
    for (int hh = 0; hh < 2; ++hh) {
      #pragma unroll
      for (int jl = 0; jl < 2; ++jl) {       // write 2 fragments (row = l16)
        int tp = jl * 16 + quad * 4;
        int g = l16 * 32 + (tp ^ ((l16 & 7) << 2));
        *(f32x4*)(scr + (g >> 8) * 1024 + wid * 256 + (g & 255)) = sa[hh * 2 + jl];
      }
      CFENCE();
      #pragma unroll
      for (int i = 0; i < 2; ++i) {          // read back row-major, store full lines
        int row = i * 8 + (lane >> 3);
        int tp = (lane & 7) * 4;
        int g = row * 32 + (tp ^ ((row & 7) << 2));
        f32x4 vv = *(const f32x4*)(scr + (g >> 8) * 1024 + wid * 256 + (g & 255));
        float* dst = score + ((size_t)bh * S_ + q0 + wid * 16 + row) * S_ + t0 + hh * 32 + tp;
        __builtin_nontemporal_store(vv, (f32x4*)dst);   // 8 lanes x 16B = 128B/row
      }
      CFENCE();
    }

    // exponentiate + row sum (overwrites sa; scratch already read out)
    float sm = 0.f;
    #pragma unroll
    for (int jt = 0; jt < 4; ++jt)
      #pragma unroll
      for (int r = 0; r < 4; ++r) { float p = __expf(sa[jt][r] - mn); sa[jt][r] = p; sm += p; }
    sm += __shfl_xor(sm, 16);
    sm += __shfl_xor(sm, 32);
    l_r = l_r * alpha + sm;
    // redistribute alpha from stat layout (q=l16) to O's C layout (q=quad*4+r)
    float al[4];
    #pragma unroll
    for (int r = 0; r < 4; ++r) al[r] = __shfl(alpha, quad * 4 + r);
    #pragma unroll
    for (int dn = 0; dn < 8; ++dn)
      #pragma unroll
      for (int r = 0; r < 4; ++r) acc_o[dn][r] *= al[r];

    // P -> LDS in A-operand layout; wave-private rows, fenced ordering
    {
      const int qrow = wid * 16 + l16;
      #pragma unroll
      for (int jt = 0; jt < 4; ++jt) {
        uint2 w; w.x = pack2bf(sa[jt][0], sa[jt][1]); w.y = pack2bf(sa[jt][2], sa[jt][3]);
        *(uint2*)(Ps + (jt >> 1) * 2048 + qrow * 32 + (jt & 1) * 16 + quad * 4) = w;
      }
    }
    CFENCE();

    // O += P V
    #pragma unroll
    for (int kkt = 0; kkt < 2; ++kkt) {
      bf16x8 pf = *(const bf16x8*)(Ps + kkt * 2048 + (wid * 16 + l16) * 32 + quad * 8);
      #pragma unroll
      for (int dn = 0; dn < 8; ++dn) {
        bf16x8 vf = *(const bf16x8*)(vsb + kkt * 4096 + (dn * 16 + l16) * 32 + quad * 8);
        acc_o[dn] = __builtin_amdgcn_mfma_f32_16x16x32_bf16(pf, vf, acc_o[dn], 0, 0, 0);
      }
    }

    // one barrier per iter: (a) all waves done reading buf (overwritten at tt+1's
    // prefetch target tt+2... i.e. next time buf is staged), (b) each wave's own
    // prefetch into buf^1 drained (vmcnt(0)) -> tile tt+1 ready for all.
    __syncthreads();
  }
  #undef STAGE_KV

  // epilogue: atten[b][h][q][d] and res[b][q][h*128+d]; l in stat layout -> shfl
  float lo[4];
  #pragma unroll
  for (int r = 0; r < 4; ++r) lo[r] = 1.0f / __shfl(l_r, quad * 4 + r);
  #pragma unroll
  for (int dn = 0; dn < 8; ++dn) {
    int d = dn * 16 + l16;
    #pragma unroll
    for (int r = 0; r < 4; ++r) {
      int q = q0 + wid * 16 + quad * 4 + r;
      float v = acc_o[dn][r] * lo[r];
      atten[((size_t)bh * S_ + q) * KD_ + d] = v;
      res[((size_t)b * S_ + q) * D_ + h * KD_ + d] = v;
    }
  }
}

// ---------------------------------------------------------------------------
extern "C" void kernel_launch(void* const* d_in, const int* in_sizes, int n_in,
                              void* d_out, int out_size, void* d_ws, size_t ws_size,
                              hipStream_t stream) {
  (void)in_sizes; (void)n_in; (void)out_size; (void)ws_size;
  const float* in_x  = (const float*)d_in[0];
  const float* W_sc  = (const float*)d_in[1];
  const float* b_sc  = (const float*)d_in[2];
  const float* W_qkv = (const float*)d_in[3];
  const float* b_qkv = (const float*)d_in[4];

  char* ws = (char*)d_ws;
  unsigned short* Xb  = (unsigned short*)ws;                          // 16,777,216 B
  unsigned short* Wt  = (unsigned short*)(ws + 16777216);             // 17,825,792 B
  unsigned short* qkv = (unsigned short*)(ws + 16777216 + 17825792);  // 18,874,368 B
  unsigned short* Vt  = (unsigned short*)(ws + 16777216 + 17825792 + 18874368);  // 1,048,576 B

  float* score    = (float*)d_out;            // 2*16*2048*2048
  float* atten    = score + 134217728;
  float* res      = atten + 8388608;
  float* shortcut = res + 8388608;

  cast_x_kernel<<<4096, 256, 0, stream>>>(in_x, Xb);
  prep_w_kernel<<<dim3(64, 136), dim3(32, 8), 0, stream>>>(W_sc, W_qkv, Wt);
  gemm_fused_kernel<<<1088, 256, 0, stream>>>(Xb, Wt, b_sc, b_qkv, shortcut, qkv);
  prep_vt_kernel<<<dim3(64, 4, 2), dim3(32, 8), 0, stream>>>(qkv, Vt);
  attn_kernel<<<1024, 256, 0, stream>>>(qkv, Vt, score, atten, res);
}